// Round 6
// baseline (1875.955 us; speedup 1.0000x reference)
//
#include <hip/hip_runtime.h>
#include <hip/hip_fp16.h>

#define B_ 64
#define M_ 512
#define N_ 512
#define D_ 128
constexpr float EPS_ = 0.05f;
constexpr float SHIFT_ = 1.25f;  // K' = exp((SHIFT - D)/EPS) fits fp8 e4m3 [~2e-3 .. 448]
constexpr int NIT_ = 200;

typedef _Float16 h2 __attribute__((ext_vector_type(2)));
typedef float f2 __attribute__((ext_vector_type(2)));

__device__ __forceinline__ unsigned h2u(h2 x) { return __builtin_bit_cast(unsigned, x); }
__device__ __forceinline__ h2 u2h(unsigned x) { return __builtin_bit_cast(h2, x); }

template <bool HI>
__device__ __forceinline__ h2 cvt_h2(unsigned w) {
    f2 f = __builtin_amdgcn_cvt_pk_f32_fp8((int)w, HI);
    return __builtin_bit_cast(h2, __builtin_amdgcn_cvt_pkrtz(f.x, f.y));
}
template <bool HI>
__device__ __forceinline__ f2 cvt_f2(unsigned w) {
    return __builtin_amdgcn_cvt_pk_f32_fp8((int)w, HI);
}

__device__ __forceinline__ float dot2f(h2 a, h2 b, float c) {
#if __has_builtin(__builtin_amdgcn_fdot2)
    return __builtin_amdgcn_fdot2(a, b, c, false);
#else
    return fmaf((float)a.x, (float)b.x, fmaf((float)a.y, (float)b.y, c));
#endif
}

// sum across each 16-lane row group via DPP (VALU only); all 16 lanes get the sum
__device__ __forceinline__ float red16(float x) {
    x += __builtin_bit_cast(float, __builtin_amdgcn_mov_dpp(__builtin_bit_cast(int, x), 0xB1, 0xF, 0xF, true));  // quad_perm xor1
    x += __builtin_bit_cast(float, __builtin_amdgcn_mov_dpp(__builtin_bit_cast(int, x), 0x4E, 0xF, 0xF, true));  // quad_perm xor2
    x += __builtin_bit_cast(float, __builtin_amdgcn_mov_dpp(__builtin_bit_cast(int, x), 0x124, 0xF, 0xF, true)); // row_ror:4
    x += __builtin_bit_cast(float, __builtin_amdgcn_mov_dpp(__builtin_bit_cast(int, x), 0x128, 0xF, 0xF, true)); // row_ror:8
    return x;
}

// ---------------------------------------------------------------------------
__global__ __launch_bounds__(256) void wmd_norms(const float* __restrict__ x,
                                                 const float* __restrict__ y,
                                                 float* __restrict__ xn,
                                                 float* __restrict__ yn) {
    int gw = (int)((blockIdx.x * blockDim.x + threadIdx.x) >> 6);
    int l = threadIdx.x & 63;
    const float* src; float* dst; int row;
    if (gw < B_ * M_) { src = x; dst = xn; row = gw; }
    else              { src = y; dst = yn; row = gw - B_ * M_; }
    float2 a = ((const float2*)(src + (size_t)row * D_))[l];
    float s = a.x * a.x + a.y * a.y;
#pragma unroll
    for (int off = 32; off; off >>= 1) s += __shfl_xor(s, off);
    if (l == 0) dst[row] = s;
}

// ---------------------------------------------------------------------------
// K'[b,i,j] = clamp(exp((SHIFT - D_ij)/EPS), 448) in fp8 e4m3
__global__ __launch_bounds__(256) void wmd_build_k(const float* __restrict__ x,
                                                   const float* __restrict__ y,
                                                   const float* __restrict__ xn,
                                                   const float* __restrict__ yn,
                                                   unsigned char* __restrict__ Kp) {
    int b = blockIdx.z, it = blockIdx.y, jt = blockIdx.x;
    __shared__ float xs[32][129];
    __shared__ float ys[32][129];
    const float4* xb = (const float4*)(x + ((size_t)b * M_ + it * 32) * D_);
    const float4* yb = (const float4*)(y + ((size_t)b * N_ + jt * 32) * D_);
    int t = threadIdx.x;
#pragma unroll
    for (int k = 0; k < 4; ++k) {
        int idx = t + k * 256;
        int r = idx >> 5, c = (idx & 31) * 4;
        float4 vx = xb[idx];
        float4 vy = yb[idx];
        xs[r][c] = vx.x; xs[r][c + 1] = vx.y; xs[r][c + 2] = vx.z; xs[r][c + 3] = vx.w;
        ys[r][c] = vy.x; ys[r][c + 1] = vy.y; ys[r][c + 2] = vy.z; ys[r][c + 3] = vy.w;
    }
    __syncthreads();
    int ti = t >> 5, tj = t & 31;
    float a0 = 0.f, a1 = 0.f, a2 = 0.f, a3 = 0.f;
    for (int d = 0; d < D_; ++d) {
        float yv = ys[tj][d];
        a0 += xs[ti][d] * yv;
        a1 += xs[ti + 8][d] * yv;
        a2 += xs[ti + 16][d] * yv;
        a3 += xs[ti + 24][d] * yv;
    }
    float ynj = yn[(size_t)b * N_ + jt * 32 + tj];
    float accs[4] = {a0, a1, a2, a3};
#pragma unroll
    for (int k = 0; k < 4; ++k) {
        int gi = it * 32 + ti + 8 * k;
        float sq = (xn[(size_t)b * M_ + gi] + ynj - 2.0f * accs[k]) * (1.0f / D_);
        float Dv = sqrtf(fmaxf(sq, 1e-12f));
        float kv = fminf(expf((SHIFT_ - Dv) * (1.0f / EPS_)), 448.0f);
        unsigned r8 = (unsigned)__builtin_amdgcn_cvt_pk_fp8_f32(kv, kv, 0, false);
        Kp[((size_t)b * M_ + gi) * N_ + jt * 32 + tj] = (unsigned char)(r8 & 0xff);
    }
}

// ---------------------------------------------------------------------------
// Persistent Sinkhorn: 1 WG (8 waves, 512 thr) per batch; whole fp8 K tile in
// VGPRs: 16 rows/lane x 32 contiguous cols = 128 VGPRs. No global traffic in loop.
// Lane l: sub = l&15 owns cols [sub*32, sub*32+32); rg = l>>4 = row-in-group.
// Wave w owns rows [w*64, w*64+64) in 16 groups of 4.
__global__ __launch_bounds__(512, 2) void wmd_sinkhorn(const unsigned char* __restrict__ K8,
                                                       float* __restrict__ wmd) {
    int b = blockIdx.x;
    const unsigned char* Kb = K8 + (size_t)b * M_ * N_;
    __shared__ h2 mrg[32][260];   // 32 sub-wave partial rows x 256 h2-cols (pad->1040B row, 16B aligned)
    __shared__ h2 v_sh[256];
    __shared__ float u_s[M_];
    __shared__ float wsum[8];
    int t = threadIdx.x, w = t >> 6, l = t & 63;
    int sub = l & 15, rg = l >> 4;
    const float pmarg = 1.0f / M_;

    // preload: kr[g][q] = 16 fp8 = cols sub*32 + q*16 .. +16 of row w*64+g*4+rg
    uint4 kr[16][2];
    {
        const unsigned char* base = Kb + ((size_t)(w * 64 + rg) * N_) + sub * 32;
#pragma unroll
        for (int g = 0; g < 16; ++g) {
            kr[g][0] = *(const uint4*)(base + (size_t)g * 4 * N_);
            kr[g][1] = *(const uint4*)(base + (size_t)g * 4 * N_ + 16);
        }
    }

    h2 vh[16];
    _Float16 one = (_Float16)1.0f;
#pragma unroll
    for (int j = 0; j < 16; ++j) vh[j] = (h2){one, one};  // v0 = 1

#pragma unroll 1
    for (int it = 0; it < NIT_; ++it) {
        h2 ca[16];
        _Float16 z = (_Float16)0.0f;
#pragma unroll
        for (int j = 0; j < 16; ++j) ca[j] = (h2){z, z};

#pragma unroll 2
        for (int g = 0; g < 16; ++g) {
            // convert this row's 32 fp8 ONCE -> 16 h2, reuse for dot and ca
            h2 kh[16];
#pragma unroll
            for (int q = 0; q < 2; ++q) {
                const unsigned* dw = (const unsigned*)&kr[g][q];
#pragma unroll
                for (int dd = 0; dd < 4; ++dd) {
                    kh[q * 8 + dd * 2]     = cvt_h2<false>(dw[dd]);
                    kh[q * 8 + dd * 2 + 1] = cvt_h2<true>(dw[dd]);
                }
            }
            float d0 = 0.f, d1 = 0.f, d2 = 0.f, d3 = 0.f;
#pragma unroll
            for (int j = 0; j < 4; ++j) {
                d0 = dot2f(kh[j],      vh[j],      d0);
                d1 = dot2f(kh[4 + j],  vh[4 + j],  d1);
                d2 = dot2f(kh[8 + j],  vh[8 + j],  d2);
                d3 = dot2f(kh[12 + j], vh[12 + j], d3);
            }
            float dot = red16((d0 + d1) + (d2 + d3));
            float rd = __builtin_amdgcn_rcpf(dot);   // = 512*u (scaled u keeps fp16 mid-range)
            if (sub == 0) u_s[w * 64 + g * 4 + rg] = rd;
            _Float16 uf = (_Float16)rd;
            h2 uh = (h2){uf, uf};
#pragma unroll
            for (int j = 0; j < 16; ++j) ca[j] = kh[j] * uh + ca[j];
        }
        // each 16-lane sub-wave writes its partial row (4 x b128)
        int mr = (w << 2) + rg;
#pragma unroll
        for (int c = 0; c < 4; ++c) {
            uint4 pk = {h2u(ca[4 * c]), h2u(ca[4 * c + 1]), h2u(ca[4 * c + 2]), h2u(ca[4 * c + 3])};
            *(uint4*)&mrg[mr][sub * 16 + 4 * c] = pk;
        }
        __syncthreads();
        // column merge: 2 lanes per h2-col; lane sums 16 of 32 partial rows
        {
            int col2 = t >> 1, half = t & 1;
            _Float16 z2 = (_Float16)0.0f;
            h2 s0 = (h2){z2, z2}, s1 = (h2){z2, z2}, s2 = (h2){z2, z2}, s3 = (h2){z2, z2};
#pragma unroll
            for (int k = 0; k < 4; ++k) {
                s0 = s0 + mrg[half * 16 + k][col2];
                s1 = s1 + mrg[half * 16 + 4 + k][col2];
                s2 = s2 + mrg[half * 16 + 8 + k][col2];
                s3 = s3 + mrg[half * 16 + 12 + k][col2];
            }
            h2 s = (s0 + s1) + (s2 + s3);
            s = s + u2h((unsigned)__shfl_xor((int)h2u(s), 1));
            if (half == 0) {
                h2 vv;
                vv.x = (_Float16)__builtin_amdgcn_rcpf((float)s.x);  // v = rcp(colsum_scaled)
                vv.y = (_Float16)__builtin_amdgcn_rcpf((float)s.y);
                v_sh[col2] = vv;
            }
        }
        __syncthreads();
#pragma unroll
        for (int q = 0; q < 2; ++q) {
            uint4 vv = *(const uint4*)&v_sh[sub * 16 + q * 8];
            vh[q * 8 + 0] = u2h(vv.x);
            vh[q * 8 + 1] = u2h(vv.y);
            vh[q * 8 + 2] = u2h(vv.z);
            vh[q * 8 + 3] = u2h(vv.w);
            uint4 vv2 = *(const uint4*)&v_sh[sub * 16 + q * 8 + 4];
            vh[q * 8 + 4] = u2h(vv2.x);
            vh[q * 8 + 5] = u2h(vv2.y);
            vh[q * 8 + 6] = u2h(vv2.z);
            vh[q * 8 + 7] = u2h(vv2.w);
        }
    }

    // Final: wmd_b = sum_ij u_i K_ij v_j * D_ij, D_ij = SHIFT - EPS*ln(K_ij)
    float acc = 0.f;
#pragma unroll 2
    for (int g = 0; g < 16; ++g) {
        float us = u_s[w * 64 + g * 4 + rg];
#pragma unroll
        for (int q = 0; q < 2; ++q) {
            const unsigned* dw = (const unsigned*)&kr[g][q];
#pragma unroll
            for (int dd = 0; dd < 4; ++dd) {
                f2 klo = cvt_f2<false>(dw[dd]);
                f2 khi = cvt_f2<true>(dw[dd]);
                h2 v0 = vh[q * 8 + dd * 2], v1 = vh[q * 8 + dd * 2 + 1];
                float kx = fmaxf(klo.x, 1e-9f), ky = fmaxf(klo.y, 1e-9f);
                acc += (us * kx * (float)v0.x) * (SHIFT_ - EPS_ * __logf(kx));
                acc += (us * ky * (float)v0.y) * (SHIFT_ - EPS_ * __logf(ky));
                kx = fmaxf(khi.x, 1e-9f); ky = fmaxf(khi.y, 1e-9f);
                acc += (us * kx * (float)v1.x) * (SHIFT_ - EPS_ * __logf(kx));
                acc += (us * ky * (float)v1.y) * (SHIFT_ - EPS_ * __logf(ky));
            }
        }
    }
#pragma unroll
    for (int off = 1; off < 64; off <<= 1) acc += __shfl_xor(acc, off);
    if (l == 0) wsum[w] = acc;
    __syncthreads();
    if (t == 0) {
        float s = 0.f;
#pragma unroll
        for (int ww = 0; ww < 8; ++ww) s += wsum[ww];
        wmd[b] = s * pmarg;
    }
}

// ---------------------------------------------------------------------------
__global__ void wmd_mse(const float* __restrict__ wmd, const float* __restrict__ labels,
                        float* __restrict__ out) {
    int l = threadIdx.x;
    float d = wmd[l] - labels[l];
    d = d * d;
#pragma unroll
    for (int off = 32; off; off >>= 1) d += __shfl_xor(d, off);
    if (l == 0) out[0] = d * (1.0f / B_);
}

// ---------------------------------------------------------------------------
extern "C" void kernel_launch(void* const* d_in, const int* in_sizes, int n_in,
                              void* d_out, int out_size, void* d_ws, size_t ws_size,
                              hipStream_t stream) {
    const float* x = (const float*)d_in[0];
    const float* y = (const float*)d_in[1];
    const float* labels = (const float*)d_in[2];
    float* out = (float*)d_out;

    char* ws = (char*)d_ws;
    unsigned char* K8 = (unsigned char*)ws;                             // 16 MiB
    size_t off = (size_t)B_ * M_ * N_;
    float* xn = (float*)(ws + off);        off += (size_t)B_ * M_ * sizeof(float);
    float* yn = (float*)(ws + off);        off += (size_t)B_ * N_ * sizeof(float);
    float* wmd = (float*)(ws + off);

    wmd_norms<<<(B_ * (M_ + N_)) / 4, 256, 0, stream>>>(x, y, xn, yn);
    wmd_build_k<<<dim3(N_ / 32, M_ / 32, B_), 256, 0, stream>>>(x, y, xn, yn, K8);
    wmd_sinkhorn<<<B_, 512, 0, stream>>>(K8, wmd);
    wmd_mse<<<1, 64, 0, stream>>>(wmd, labels, out);
}

// Round 7
// 1818.361 us; speedup vs baseline: 1.0317x; 1.0317x over previous
//
#include <hip/hip_runtime.h>
#include <hip/hip_fp16.h>

#define B_ 64
#define M_ 512
#define N_ 512
#define D_ 128
constexpr float EPS_ = 0.05f;
constexpr float SHIFT_ = 1.25f;  // K' = exp((SHIFT - D)/EPS) fits fp8 e4m3 [~2e-3 .. 448]
constexpr int NIT_ = 200;

typedef _Float16 h2 __attribute__((ext_vector_type(2)));
typedef float f2 __attribute__((ext_vector_type(2)));

__device__ __forceinline__ unsigned h2u(h2 x) { return __builtin_bit_cast(unsigned, x); }
__device__ __forceinline__ h2 u2h(unsigned x) { return __builtin_bit_cast(h2, x); }

template <bool HI>
__device__ __forceinline__ h2 cvt_h2(unsigned w) {
#if __has_builtin(__builtin_amdgcn_cvt_scalef32_pk_f16_fp8)
    return __builtin_bit_cast(h2, __builtin_amdgcn_cvt_scalef32_pk_f16_fp8(w, 1.0f, HI));
#else
    f2 f = __builtin_amdgcn_cvt_pk_f32_fp8((int)w, HI);
    return __builtin_bit_cast(h2, __builtin_amdgcn_cvt_pkrtz(f.x, f.y));
#endif
}
template <bool HI>
__device__ __forceinline__ f2 cvt_f2(unsigned w) {
    return __builtin_amdgcn_cvt_pk_f32_fp8((int)w, HI);
}

__device__ __forceinline__ float dot2f(h2 a, h2 b, float c) {
#if __has_builtin(__builtin_amdgcn_fdot2)
    return __builtin_amdgcn_fdot2(a, b, c, false);
#else
    return fmaf((float)a.x, (float)b.x, fmaf((float)a.y, (float)b.y, c));
#endif
}

// sum across each 16-lane group via DPP (VALU only); all 16 lanes get the sum
__device__ __forceinline__ float red16(float x) {
    x += __builtin_bit_cast(float, __builtin_amdgcn_mov_dpp(__builtin_bit_cast(int, x), 0xB1, 0xF, 0xF, true));  // quad_perm xor1
    x += __builtin_bit_cast(float, __builtin_amdgcn_mov_dpp(__builtin_bit_cast(int, x), 0x4E, 0xF, 0xF, true));  // quad_perm xor2
    x += __builtin_bit_cast(float, __builtin_amdgcn_mov_dpp(__builtin_bit_cast(int, x), 0x124, 0xF, 0xF, true)); // row_ror:4
    x += __builtin_bit_cast(float, __builtin_amdgcn_mov_dpp(__builtin_bit_cast(int, x), 0x128, 0xF, 0xF, true)); // row_ror:8
    return x;
}

// ---------------------------------------------------------------------------
__global__ __launch_bounds__(256) void wmd_norms(const float* __restrict__ x,
                                                 const float* __restrict__ y,
                                                 float* __restrict__ xn,
                                                 float* __restrict__ yn) {
    int gw = (int)((blockIdx.x * blockDim.x + threadIdx.x) >> 6);
    int l = threadIdx.x & 63;
    const float* src; float* dst; int row;
    if (gw < B_ * M_) { src = x; dst = xn; row = gw; }
    else              { src = y; dst = yn; row = gw - B_ * M_; }
    float2 a = ((const float2*)(src + (size_t)row * D_))[l];
    float s = a.x * a.x + a.y * a.y;
#pragma unroll
    for (int off = 32; off; off >>= 1) s += __shfl_xor(s, off);
    if (l == 0) dst[row] = s;
}

// ---------------------------------------------------------------------------
// K'[b,i,j] = clamp(exp((SHIFT - D_ij)/EPS), 448) in fp8 e4m3
__global__ __launch_bounds__(256) void wmd_build_k(const float* __restrict__ x,
                                                   const float* __restrict__ y,
                                                   const float* __restrict__ xn,
                                                   const float* __restrict__ yn,
                                                   unsigned char* __restrict__ Kp) {
    int b = blockIdx.z, it = blockIdx.y, jt = blockIdx.x;
    __shared__ float xs[32][129];
    __shared__ float ys[32][129];
    const float4* xb = (const float4*)(x + ((size_t)b * M_ + it * 32) * D_);
    const float4* yb = (const float4*)(y + ((size_t)b * N_ + jt * 32) * D_);
    int t = threadIdx.x;
#pragma unroll
    for (int k = 0; k < 4; ++k) {
        int idx = t + k * 256;
        int r = idx >> 5, c = (idx & 31) * 4;
        float4 vx = xb[idx];
        float4 vy = yb[idx];
        xs[r][c] = vx.x; xs[r][c + 1] = vx.y; xs[r][c + 2] = vx.z; xs[r][c + 3] = vx.w;
        ys[r][c] = vy.x; ys[r][c + 1] = vy.y; ys[r][c + 2] = vy.z; ys[r][c + 3] = vy.w;
    }
    __syncthreads();
    int ti = t >> 5, tj = t & 31;
    float a0 = 0.f, a1 = 0.f, a2 = 0.f, a3 = 0.f;
    for (int d = 0; d < D_; ++d) {
        float yv = ys[tj][d];
        a0 += xs[ti][d] * yv;
        a1 += xs[ti + 8][d] * yv;
        a2 += xs[ti + 16][d] * yv;
        a3 += xs[ti + 24][d] * yv;
    }
    float ynj = yn[(size_t)b * N_ + jt * 32 + tj];
    float accs[4] = {a0, a1, a2, a3};
#pragma unroll
    for (int k = 0; k < 4; ++k) {
        int gi = it * 32 + ti + 8 * k;
        float sq = (xn[(size_t)b * M_ + gi] + ynj - 2.0f * accs[k]) * (1.0f / D_);
        float Dv = sqrtf(fmaxf(sq, 1e-12f));
        float kv = fminf(expf((SHIFT_ - Dv) * (1.0f / EPS_)), 448.0f);
        unsigned r8 = (unsigned)__builtin_amdgcn_cvt_pk_fp8_f32(kv, kv, 0, false);
        Kp[((size_t)b * M_ + gi) * N_ + jt * 32 + tj] = (unsigned char)(r8 & 0xff);
    }
}

// ---------------------------------------------------------------------------
// Persistent Sinkhorn: 1 WG (8 waves, 512 thr) per batch; whole fp8 K tile in
// VGPRs: 16 rows/lane x 32 contiguous cols = 128 VGPRs (ALL statically indexed
// -> full unroll everywhere; rule: runtime-indexed arrays go to scratch).
// Lane l: sub = l&15 owns cols [sub*32, sub*32+32); rg = l>>4 = row-in-group.
// Wave w owns rows [w*64, w*64+64) in 16 groups of 4.
// LDS column addressing uses XOR-rotation swizzle ((c + (sub>>1))&3) on both
// write and read sides -> merge/v traffic is 2-way/broadcast (conflict-free).
__global__ __attribute__((amdgpu_flat_work_group_size(512, 512), amdgpu_waves_per_eu(2, 2)))
void wmd_sinkhorn(const unsigned char* __restrict__ K8, float* __restrict__ wmd) {
    int b = blockIdx.x;
    const unsigned char* Kb = K8 + (size_t)b * M_ * N_;
    __shared__ h2 mrg[32][264];   // 32 subwave partial rows; stride 264 dw (mod 32 = 8: rg spreads banks)
    __shared__ h2 v_sh[256];
    __shared__ float u_s[M_];
    __shared__ float wsum[8];
    int t = threadIdx.x, w = t >> 6, l = t & 63;
    int sub = l & 15, rg = l >> 4;
    int rot = (sub >> 1) & 3;     // per-lane column rotation for LDS swizzle
    const float pmarg = 1.0f / M_;

    // preload: kr[g][q] = 16 fp8 = cols sub*32 + q*16 .. +16 of row w*64+g*4+rg
    uint4 kr[16][2];
    {
        const unsigned char* base = Kb + ((size_t)(w * 64 + rg) * N_) + sub * 32;
#pragma unroll
        for (int g = 0; g < 16; ++g) {
            kr[g][0] = *(const uint4*)(base + (size_t)g * 4 * N_);
            kr[g][1] = *(const uint4*)(base + (size_t)g * 4 * N_ + 16);
        }
    }

    h2 vh[16];
    _Float16 one = (_Float16)1.0f;
#pragma unroll
    for (int j = 0; j < 16; ++j) vh[j] = (h2){one, one};  // v0 = 1

#pragma unroll 1
    for (int it = 0; it < NIT_; ++it) {
        h2 ca[16];
        _Float16 z = (_Float16)0.0f;
#pragma unroll
        for (int j = 0; j < 16; ++j) ca[j] = (h2){z, z};

#pragma unroll
        for (int g = 0; g < 16; ++g) {
            // convert this row's 32 fp8 ONCE -> 16 h2, reuse for dot and ca
            h2 kh[16];
#pragma unroll
            for (int q = 0; q < 2; ++q) {
                const unsigned* dw = (const unsigned*)&kr[g][q];
#pragma unroll
                for (int dd = 0; dd < 4; ++dd) {
                    kh[q * 8 + dd * 2]     = cvt_h2<false>(dw[dd]);
                    kh[q * 8 + dd * 2 + 1] = cvt_h2<true>(dw[dd]);
                }
            }
            float d0 = 0.f, d1 = 0.f, d2 = 0.f, d3 = 0.f;
#pragma unroll
            for (int j = 0; j < 4; ++j) {
                d0 = dot2f(kh[j],      vh[j],      d0);
                d1 = dot2f(kh[4 + j],  vh[4 + j],  d1);
                d2 = dot2f(kh[8 + j],  vh[8 + j],  d2);
                d3 = dot2f(kh[12 + j], vh[12 + j], d3);
            }
            float dot = red16((d0 + d1) + (d2 + d3));
            float rd = __builtin_amdgcn_rcpf(dot);   // = 512*u (scaled u stays fp16 mid-range)
            if (sub == 0) u_s[w * 64 + g * 4 + rg] = rd;
            _Float16 uf = (_Float16)rd;
            h2 uh = (h2){uf, uf};
#pragma unroll
            for (int j = 0; j < 16; ++j) ca[j] = kh[j] * uh + ca[j];
        }
        // each 16-lane subwave writes its partial row (4 x b128, swizzled cols)
        int mr = (w << 2) + rg;
#pragma unroll
        for (int c = 0; c < 4; ++c) {
            uint4 pk = {h2u(ca[4 * c]), h2u(ca[4 * c + 1]), h2u(ca[4 * c + 2]), h2u(ca[4 * c + 3])};
            *(uint4*)&mrg[mr][sub * 16 + 4 * ((c + rot) & 3)] = pk;
        }
        __syncthreads();
        // column merge: 2 lanes per h2-col; lane sums 16 of 32 partial rows
        {
            int col2 = t >> 1, half = t & 1;
            int phys = (col2 & ~12) | ((((col2 >> 2) & 3) + ((col2 >> 4) >> 1) & 3) << 2);
            _Float16 z2 = (_Float16)0.0f;
            h2 s0 = (h2){z2, z2}, s1 = (h2){z2, z2}, s2 = (h2){z2, z2}, s3 = (h2){z2, z2};
#pragma unroll
            for (int k = 0; k < 4; ++k) {
                s0 = s0 + mrg[half * 16 + k][phys];
                s1 = s1 + mrg[half * 16 + 4 + k][phys];
                s2 = s2 + mrg[half * 16 + 8 + k][phys];
                s3 = s3 + mrg[half * 16 + 12 + k][phys];
            }
            h2 s = (s0 + s1) + (s2 + s3);
            s = s + u2h((unsigned)__shfl_xor((int)h2u(s), 1));
            if (half == 0) {
                h2 vv;
                vv.x = (_Float16)__builtin_amdgcn_rcpf((float)s.x);  // v = rcp(colsum_scaled)
                vv.y = (_Float16)__builtin_amdgcn_rcpf((float)s.y);
                v_sh[phys] = vv;
            }
        }
        __syncthreads();
        // reload vh (b128 at swizzled position contains logical c=q, i=0..3)
#pragma unroll
        for (int q = 0; q < 4; ++q) {
            uint4 vv = *(const uint4*)&v_sh[sub * 16 + 4 * ((q + rot) & 3)];
            vh[q * 4 + 0] = u2h(vv.x);
            vh[q * 4 + 1] = u2h(vv.y);
            vh[q * 4 + 2] = u2h(vv.z);
            vh[q * 4 + 3] = u2h(vv.w);
        }
    }

    // Final: wmd_b = sum_ij u_i K_ij v_j * D_ij, D_ij = SHIFT - EPS*ln(K_ij)
    float acc = 0.f;
#pragma unroll
    for (int g = 0; g < 16; ++g) {
        float us = u_s[w * 64 + g * 4 + rg];
#pragma unroll
        for (int q = 0; q < 2; ++q) {
            const unsigned* dw = (const unsigned*)&kr[g][q];
#pragma unroll
            for (int dd = 0; dd < 4; ++dd) {
                f2 klo = cvt_f2<false>(dw[dd]);
                f2 khi = cvt_f2<true>(dw[dd]);
                h2 v0 = vh[q * 8 + dd * 2], v1 = vh[q * 8 + dd * 2 + 1];
                float kx = fmaxf(klo.x, 1e-9f), ky = fmaxf(klo.y, 1e-9f);
                acc += (us * kx * (float)v0.x) * (SHIFT_ - EPS_ * __logf(kx));
                acc += (us * ky * (float)v0.y) * (SHIFT_ - EPS_ * __logf(ky));
                kx = fmaxf(khi.x, 1e-9f); ky = fmaxf(khi.y, 1e-9f);
                acc += (us * kx * (float)v1.x) * (SHIFT_ - EPS_ * __logf(kx));
                acc += (us * ky * (float)v1.y) * (SHIFT_ - EPS_ * __logf(ky));
            }
        }
    }
#pragma unroll
    for (int off = 1; off < 64; off <<= 1) acc += __shfl_xor(acc, off);
    if (l == 0) wsum[w] = acc;
    __syncthreads();
    if (t == 0) {
        float s = 0.f;
#pragma unroll
        for (int ww = 0; ww < 8; ++ww) s += wsum[ww];
        wmd[b] = s * pmarg;
    }
}

// ---------------------------------------------------------------------------
__global__ void wmd_mse(const float* __restrict__ wmd, const float* __restrict__ labels,
                        float* __restrict__ out) {
    int l = threadIdx.x;
    float d = wmd[l] - labels[l];
    d = d * d;
#pragma unroll
    for (int off = 32; off; off >>= 1) d += __shfl_xor(d, off);
    if (l == 0) out[0] = d * (1.0f / B_);
}

// ---------------------------------------------------------------------------
extern "C" void kernel_launch(void* const* d_in, const int* in_sizes, int n_in,
                              void* d_out, int out_size, void* d_ws, size_t ws_size,
                              hipStream_t stream) {
    const float* x = (const float*)d_in[0];
    const float* y = (const float*)d_in[1];
    const float* labels = (const float*)d_in[2];
    float* out = (float*)d_out;

    char* ws = (char*)d_ws;
    unsigned char* K8 = (unsigned char*)ws;                             // 16 MiB
    size_t off = (size_t)B_ * M_ * N_;
    float* xn = (float*)(ws + off);        off += (size_t)B_ * M_ * sizeof(float);
    float* yn = (float*)(ws + off);        off += (size_t)B_ * N_ * sizeof(float);
    float* wmd = (float*)(ws + off);

    wmd_norms<<<(B_ * (M_ + N_)) / 4, 256, 0, stream>>>(x, y, xn, yn);
    wmd_build_k<<<dim3(N_ / 32, M_ / 32, B_), 256, 0, stream>>>(x, y, xn, yn, K8);
    wmd_sinkhorn<<<B_, 512, 0, stream>>>(K8, wmd);
    wmd_mse<<<1, 64, 0, stream>>>(wmd, labels, out);
}